// Round 13
// baseline (159.447 us; speedup 1.0000x reference)
//
#include <hip/hip_runtime.h>
#include <hip/hip_bf16.h>

// Problem: B=4, H=W=64 -> N=4096 tokens, C=64, d=8
#define BATCH 4
#define NTOK 4096
#define CCH 64
#define KSPLIT 2
#define KPB (NTOK / KSPLIT)   // 2048 keys per attn block
#define NTILE (KPB / 64)      // 32 key tiles per block
#define TPW (NTILE / 4)       // 8 tiles per wave (waves own disjoint tiles)

// Schraudolph-to-bf16: p_bits16 = (int)(s*128*log2e + SBIAS), scale folded
// into Q (proj), bias folded into the S-MFMA accumulator seed.
#define QSCALE 184.66496523f   // 128 * log2(e)
#define SBIAS  16251.0f        // 127*128 - 5.0 (optimal bias, 7-bit mantissa)

typedef short s16x8 __attribute__((ext_vector_type(8)));
typedef float f32x4 __attribute__((ext_vector_type(4)));

static __device__ __forceinline__ unsigned short f2bf(float f) {
    union { __hip_bfloat16 h; unsigned short u; } cv;
    cv.h = __float2bfloat16(f);
    return cv.u;
}
static __device__ __forceinline__ float bf2f(unsigned short u) {
    union { unsigned int u; float f; } c; c.u = ((unsigned)u) << 16;
    return c.f;
}
static __device__ __forceinline__ float bf_split(float f, unsigned short& h) {
    h = f2bf(f);
    return f - bf2f(h);
}
static __device__ __forceinline__ unsigned pack_rne(float a, float b) {
    return ((unsigned)f2bf(b) << 16) | f2bf(a);
}
// pack two Schraudolph bf16 bit-patterns (values positive, < 32768)
static __device__ __forceinline__ unsigned pack_bits(float a, float b) {
    return ((unsigned)(int)b << 16) | (unsigned)(int)a;
}

// ---------------------------------------------------------------------------
// Projections (proven).  Also zeroes the attn fixup tickets (block 0) —
// stream order guarantees visibility before attn.
//   Qpack[b][n][32] bf16 = [qh|ql|qh|0]  with q PRE-SCALED by QSCALE
//   Kpack[b][n][16] bf16 = [kh|kl]
//   vT[b][c][n] bf16 — V^T via MFMA (bf16 x staged once in LDS)
// grid: B*128 blocks (32-token tiles), 256 threads.
// ---------------------------------------------------------------------------
__global__ __launch_bounds__(256) void proj_kernel(
    const float* __restrict__ xg,
    const float* __restrict__ Wf, const float* __restrict__ bf_,
    const float* __restrict__ Wg, const float* __restrict__ bg,
    const float* __restrict__ Wh, const float* __restrict__ bh,
    unsigned short* __restrict__ Qp, unsigned short* __restrict__ Kp,
    unsigned short* __restrict__ vTg, int* __restrict__ cnt)
{
    __shared__ float xS[32 * 68];            // fp32 x tile (q/k path)
    __shared__ unsigned short xbS[32 * 72];  // bf16 x tile, 64 ch/row
    __shared__ float WfT[8 * 68];
    __shared__ float WgT[8 * 68];
    __shared__ unsigned short vtS[64 * 40];  // V^T tile [cout][32 tok + pad]

    const int t = threadIdx.x;
    const int b = blockIdx.x >> 7;
    const int n0 = (blockIdx.x & 127) * 32;

    if (blockIdx.x == 0 && t < BATCH * 64) cnt[t] = 0;   // fixup tickets

    const float* xrow = xg + ((size_t)b * NTOK + n0) * CCH;
    for (int f = t; f < 512; f += 256) {
        int r = f >> 4, c4 = (f & 15) * 4;
        float4 v = *(const float4*)(xrow + r * 64 + c4);
        *(float4*)(xS + r * 68 + c4) = v;
        uint2 pk = { pack_rne(v.x, v.y), pack_rne(v.z, v.w) };
        *(uint2*)(xbS + r * 72 + c4) = pk;
    }
    for (int e = t; e < 512; e += 256) {
        int ci = e >> 3, j = e & 7;
        WfT[j * 68 + ci] = Wf[e];
        WgT[j * 68 + ci] = Wg[e];
    }
    __syncthreads();

    const int w = t >> 6, lane = t & 63, ml = lane & 15, quad = lane >> 4;

    // ---- V^T via MFMA: wave w owns couts w*16..w*16+15
    {
        s16x8 a0, a1;   // A[m=cout][k=cin] = Wh[cin][cout]
        #pragma unroll
        for (int j = 0; j < 8; ++j) {
            a0[j] = (short)f2bf(Wh[(quad * 8 + j) * 64 + w * 16 + ml]);
            a1[j] = (short)f2bf(Wh[(32 + quad * 8 + j) * 64 + w * 16 + ml]);
        }
        #pragma unroll
        for (int nf = 0; nf < 2; ++nf) {
            int tok = nf * 16 + ml;
            s16x8 b0 = *(const s16x8*)(xbS + tok * 72 + quad * 8);
            s16x8 b1 = *(const s16x8*)(xbS + tok * 72 + 32 + quad * 8);
            f32x4 cc = __builtin_amdgcn_mfma_f32_16x16x32_bf16(a0, b0, (f32x4){0.f,0.f,0.f,0.f}, 0, 0, 0);
            cc = __builtin_amdgcn_mfma_f32_16x16x32_bf16(a1, b1, cc, 0, 0, 0);
            #pragma unroll
            for (int reg = 0; reg < 4; ++reg) {
                int cout = w * 16 + quad * 4 + reg;
                vtS[cout * 40 + nf * 16 + ml] = f2bf(cc[reg] + bh[cout]);
            }
        }
    }

    // ---- q/k: thread (r = t>>3, j = t&7): fp32 VALU + Dekker pack
    {
        int r = t >> 3, j = t & 7;
        float q = bf_[j], k = bg[j];
        for (int ci = 0; ci < 64; ci += 4) {
            float4 x4 = *(const float4*)(xS + r * 68 + ci);
            float4 wf4 = *(const float4*)(WfT + j * 68 + ci);
            float4 wg4 = *(const float4*)(WgT + j * 68 + ci);
            q += x4.x * wf4.x + x4.y * wf4.y + x4.z * wf4.z + x4.w * wf4.w;
            k += x4.x * wg4.x + x4.y * wg4.y + x4.z * wg4.z + x4.w * wg4.w;
        }
        q *= QSCALE;   // fold Schraudolph scale (128*log2e) into Q
        unsigned short qh, kh;
        float qres = bf_split(q, qh);
        float kres = bf_split(k, kh);
        unsigned short ql = f2bf(qres), kl = f2bf(kres);
        size_t qbase = ((size_t)b * NTOK + n0 + r) * 32;
        Qp[qbase + j]      = qh;
        Qp[qbase + 8 + j]  = ql;
        Qp[qbase + 16 + j] = qh;
        Qp[qbase + 24 + j] = 0;
        size_t kbase = ((size_t)b * NTOK + n0 + r) * 16;
        Kp[kbase + j]     = kh;
        Kp[kbase + 8 + j] = kl;
    }
    __syncthreads();

    // ---- coalesced vT store
    {
        int c_ = t >> 2, chunk = t & 3;
        uint4 v = *(const uint4*)(vtS + c_ * 40 + chunk * 8);
        *(uint4*)(vTg + ((size_t)b * CCH + c_) * NTOK + n0 + chunk * 8) = v;
    }
}

// ---------------------------------------------------------------------------
// Attention — R9 config (empirical optimum: KSPLIT=2, K in 64KB LDS,
// launch_bounds(256,2) -> 2 blocks/CU with full registers), Schraudolph
// softmax, barrier-free K-loop — PLUS fused split-K combine: the second
// block of each (b,qt) pair (device-scope atomic ticket) reads the other
// split's partial and writes the final gamma*O/l + x. No combine kernel.
// grid = B*64*KSPLIT = 512 blocks, 256 thr.
// ---------------------------------------------------------------------------
__global__ __launch_bounds__(256, 2) void attn_kernel(
    const float* __restrict__ xg,
    const unsigned short* __restrict__ Qp,
    const unsigned short* __restrict__ Kp,
    const unsigned short* __restrict__ vTg,
    const float* __restrict__ gammaPtr,
    unsigned short* __restrict__ Opart,
    float* __restrict__ lpart,
    int* __restrict__ cnt,
    float* __restrict__ out)
{
    __shared__ unsigned short KC[KPB * 16];   // [key][kh8|kl8], 64 KB
    __shared__ int lastFlag;

    const int t = threadIdx.x;
    const int blk = blockIdx.x;
    const int b = blk >> 7;
    const int qt = (blk >> 1) & 63;
    const int ks = blk & 1;
    const int m0 = qt * 64;
    const int kb0 = ks * KPB;
    const int w = t >> 6, lane = t & 63;
    const int ml = lane & 15, quad = lane >> 4;

    const unsigned short* qpb = Qp + (size_t)b * NTOK * 32;
    const unsigned short* kpb = Kp + (size_t)b * NTOK * 16;
    const unsigned short* vtb = vTg + (size_t)b * CCH * NTOK;

    for (int kk = t; kk < KPB; kk += 256) {
        const unsigned short* src = kpb + (size_t)(kb0 + kk) * 16;
        *(uint4*)(&KC[kk * 16])     = *(const uint4*)(src);
        *(uint4*)(&KC[kk * 16 + 8]) = *(const uint4*)(src + 8);
    }

    s16x8 qf[4];
    #pragma unroll
    for (int qg = 0; qg < 4; ++qg)
        qf[qg] = *(const s16x8*)(qpb + (size_t)(m0 + qg * 16 + ml) * 32 + quad * 8);

    const int keyA = 8 * (ml >> 2) + (ml & 3);   // permuted key row
    const int khsel = (quad == 2) ? 8 : 0;       // quad0,1,3->kh  quad2->kl

    s16x8 ones;
    #pragma unroll
    for (int i = 0; i < 8; ++i) ones[i] = (short)0x3F80;

    f32x4 o[4][4];
    f32x4 lac[4];
    #pragma unroll
    for (int cg = 0; cg < 4; ++cg)
        #pragma unroll
        for (int qg = 0; qg < 4; ++qg) o[cg][qg] = (f32x4){0.f,0.f,0.f,0.f};
    #pragma unroll
    for (int qg = 0; qg < 4; ++qg) lac[qg] = (f32x4){0.f,0.f,0.f,0.f};
    const f32x4 sb = {SBIAS, SBIAS, SBIAS, SBIAS};   // Schraudolph bias seed

    __syncthreads();   // KC visible; no more barriers until epilogue

    const int tile0 = w * TPW;
    s16x8 kf0 = *(const s16x8*)(&KC[(tile0 * 64 + keyA) * 16 + khsel]);
    s16x8 kf1 = *(const s16x8*)(&KC[(tile0 * 64 + keyA + 4) * 16 + khsel]);
    s16x8 kf2 = *(const s16x8*)(&KC[(tile0 * 64 + 32 + keyA) * 16 + khsel]);
    s16x8 kf3 = *(const s16x8*)(&KC[(tile0 * 64 + 36 + keyA) * 16 + khsel]);

    for (int i = 0; i < TPW; ++i) {
        const int tile = tile0 + i;
        const int kb = kb0 + tile * 64;

        // V A-frags for this tile (global/L2, consumed after softmax chain)
        s16x8 vf[4][2];
        #pragma unroll
        for (int cg = 0; cg < 4; ++cg) {
            const unsigned short* vr = vtb + (size_t)(cg * 16 + ml) * NTOK + kb + quad * 8;
            vf[cg][0] = *(const s16x8*)(vr);
            vf[cg][1] = *(const s16x8*)(vr + 32);
        }
        const int tn = (i + 1 < TPW) ? tile + 1 : tile0;
        s16x8 kn0 = *(const s16x8*)(&KC[(tn * 64 + keyA) * 16 + khsel]);
        s16x8 kn1 = *(const s16x8*)(&KC[(tn * 64 + keyA + 4) * 16 + khsel]);
        s16x8 kn2 = *(const s16x8*)(&KC[(tn * 64 + 32 + keyA) * 16 + khsel]);
        s16x8 kn3 = *(const s16x8*)(&KC[(tn * 64 + 36 + keyA) * 16 + khsel]);

        // S (bias-seeded) -> p bits via int cast; lands in PV B-layout
        union { unsigned u[4]; s16x8 h; } P0[4], P1[4];
        #pragma unroll
        for (int qg = 0; qg < 4; ++qg) {
            f32x4 sA0 = __builtin_amdgcn_mfma_f32_16x16x32_bf16(kf0, qf[qg], sb, 0, 0, 0);
            f32x4 sB0 = __builtin_amdgcn_mfma_f32_16x16x32_bf16(kf1, qf[qg], sb, 0, 0, 0);
            f32x4 sA1 = __builtin_amdgcn_mfma_f32_16x16x32_bf16(kf2, qf[qg], sb, 0, 0, 0);
            f32x4 sB1 = __builtin_amdgcn_mfma_f32_16x16x32_bf16(kf3, qf[qg], sb, 0, 0, 0);
            P0[qg].u[0] = pack_bits(sA0[0], sA0[1]);
            P0[qg].u[1] = pack_bits(sA0[2], sA0[3]);
            P0[qg].u[2] = pack_bits(sB0[0], sB0[1]);
            P0[qg].u[3] = pack_bits(sB0[2], sB0[3]);
            P1[qg].u[0] = pack_bits(sA1[0], sA1[1]);
            P1[qg].u[1] = pack_bits(sA1[2], sA1[3]);
            P1[qg].u[2] = pack_bits(sB1[0], sB1[1]);
            P1[qg].u[3] = pack_bits(sB1[2], sB1[3]);
        }
        kf0 = kn0; kf1 = kn1; kf2 = kn2; kf3 = kn3;

        // l += ones * P
        #pragma unroll
        for (int qg = 0; qg < 4; ++qg) {
            lac[qg] = __builtin_amdgcn_mfma_f32_16x16x32_bf16(ones, P0[qg].h, lac[qg], 0, 0, 0);
            lac[qg] = __builtin_amdgcn_mfma_f32_16x16x32_bf16(ones, P1[qg].h, lac[qg], 0, 0, 0);
        }
        // O^T += V^T * P
        #pragma unroll
        for (int cg = 0; cg < 4; ++cg)
            #pragma unroll
            for (int qg = 0; qg < 4; ++qg) {
                o[cg][qg] = __builtin_amdgcn_mfma_f32_16x16x32_bf16(vf[cg][0], P0[qg].h, o[cg][qg], 0, 0, 0);
                o[cg][qg] = __builtin_amdgcn_mfma_f32_16x16x32_bf16(vf[cg][1], P1[qg].h, o[cg][qg], 0, 0, 0);
            }
    }

    // ---- epilogue: fp32 reduction across 4 waves via LDS (reuse KC)
    float* OL = (float*)KC;          // [64 query][68], 17.4 KB
    float* lL = OL + 64 * 68;        // [64]
    #pragma unroll
    for (int r = 0; r < 4; ++r) {
        __syncthreads();
        if (w == r) {
            #pragma unroll
            for (int cg = 0; cg < 4; ++cg)
                #pragma unroll
                for (int qg = 0; qg < 4; ++qg) {
                    f32x4* p = (f32x4*)(&OL[(qg * 16 + ml) * 68 + cg * 16 + quad * 4]);
                    if (r == 0) *p = o[cg][qg];
                    else {
                        f32x4 v = *p;
                        v[0] += o[cg][qg][0]; v[1] += o[cg][qg][1];
                        v[2] += o[cg][qg][2]; v[3] += o[cg][qg][3];
                        *p = v;
                    }
                }
            if (quad == 0) {
                #pragma unroll
                for (int qg = 0; qg < 4; ++qg) {
                    if (r == 0) lL[qg * 16 + ml] = lac[qg][0];
                    else        lL[qg * 16 + ml] += lac[qg][0];
                }
            }
        }
    }
    __syncthreads();

    // ---- write own partial (bf16 O + fp32 l)
    {
        int q = t >> 2, c0 = (t & 3) * 16;
        alignas(16) unsigned short us[16];
        #pragma unroll
        for (int k = 0; k < 16; ++k) us[k] = f2bf(OL[q * 68 + c0 + k]);
        size_t obase = ((size_t)ks * (BATCH * NTOK) + (size_t)b * NTOK + m0 + q) * 64 + c0;
        *(uint4*)(Opart + obase)     = *(uint4*)(us);
        *(uint4*)(Opart + obase + 8) = *(uint4*)(us + 8);
    }
    if (t < 64)
        lpart[ks * (BATCH * NTOK) + b * NTOK + m0 + t] = lL[t];

    // ---- split-K fixup: second block of this (b,qt) combines and writes out
    __threadfence();
    if (t == 0) {
        int old = atomicAdd(&cnt[b * 64 + qt], 1);
        lastFlag = (old == 1);
    }
    __syncthreads();
    if (lastFlag) {
        const int os = ks ^ 1;
        const float gamma = gammaPtr[0];
        const int q = t >> 2, c0 = (t & 3) * 16;
        const float lother =
            *(volatile const float*)(lpart + os * (BATCH * NTOK) + b * NTOK + m0 + q);
        const float gi = gamma / (lL[q] + lother);
        size_t pb = ((size_t)os * (BATCH * NTOK) + (size_t)b * NTOK + m0 + q) * 64 + c0;
        volatile const unsigned* op = (volatile const unsigned*)(Opart + pb);
        size_t base = ((size_t)b * NTOK + m0 + q) * CCH + c0;
        #pragma unroll
        for (int u = 0; u < 8; ++u) {
            unsigned pk = op[u];
            float o0 = OL[q * 68 + c0 + u * 2 + 0] + bf2f((unsigned short)(pk & 0xFFFF));
            float o1 = OL[q * 68 + c0 + u * 2 + 1] + bf2f((unsigned short)(pk >> 16));
            float2 x2 = *(const float2*)(xg + base + u * 2);
            float2 r;
            r.x = gi * o0 + x2.x;
            r.y = gi * o1 + x2.y;
            *(float2*)(out + base + u * 2) = r;
        }
    }
}

extern "C" void kernel_launch(void* const* d_in, const int* in_sizes, int n_in,
                              void* d_out, int out_size, void* d_ws, size_t ws_size,
                              hipStream_t stream) {
    const float* x  = (const float*)d_in[0];
    const float* Wf = (const float*)d_in[1];
    const float* bf = (const float*)d_in[2];
    const float* Wg = (const float*)d_in[3];
    const float* bg = (const float*)d_in[4];
    const float* Wh = (const float*)d_in[5];
    const float* bh = (const float*)d_in[6];
    const float* gamma = (const float*)d_in[7];
    float* out = (float*)d_out;

    // ws: Qp 1MB @0 | Kp 512KB @1MB | vT 2MB @2MB | Opart 4MB @4MB |
    //     lpart 128KB @8MB | cnt 1KB @9MB
    char* ws = (char*)d_ws;
    unsigned short* Qp    = (unsigned short*)ws;
    unsigned short* Kp    = (unsigned short*)(ws + (1u << 20));
    unsigned short* vTg   = (unsigned short*)(ws + (2u << 20));
    unsigned short* Opart = (unsigned short*)(ws + (4u << 20));
    float*          lpart = (float*)(ws + (8u << 20));
    int*            cnt   = (int*)(ws + (9u << 20));

    proj_kernel<<<BATCH * 128, 256, 0, stream>>>(x, Wf, bf, Wg, bg, Wh, bh,
                                                 Qp, Kp, vTg, cnt);
    attn_kernel<<<BATCH * 64 * KSPLIT, 256, 0, stream>>>(x, Qp, Kp, vTg, gamma,
                                                         Opart, lpart, cnt, out);
}

// Round 14
// 99.708 us; speedup vs baseline: 1.5991x; 1.5991x over previous
//
#include <hip/hip_runtime.h>
#include <hip/hip_bf16.h>

// Problem: B=4, H=W=64 -> N=4096 tokens, C=64, d=8
#define BATCH 4
#define NTOK 4096
#define CCH 64
#define KSPLIT 2
#define KPB (NTOK / KSPLIT)   // 2048 keys per attn block
#define NTILE (KPB / 64)      // 32 key tiles per block
#define TPW (NTILE / 4)       // 8 tiles per wave (waves own disjoint tiles)

// Schraudolph-to-bf16: p_bits16 = (int)(s*128*log2e + SBIAS), scale folded
// into Q (proj), bias folded into the S-MFMA accumulator seed.
#define QSCALE 184.66496523f   // 128 * log2(e)
#define SBIAS  16251.0f        // 127*128 - 5.0 (optimal bias, 7-bit mantissa)

typedef short s16x8 __attribute__((ext_vector_type(8)));
typedef float f32x4 __attribute__((ext_vector_type(4)));

static __device__ __forceinline__ unsigned short f2bf(float f) {
    union { __hip_bfloat16 h; unsigned short u; } cv;
    cv.h = __float2bfloat16(f);
    return cv.u;
}
static __device__ __forceinline__ float bf2f(unsigned short u) {
    union { unsigned int u; float f; } c; c.u = ((unsigned)u) << 16;
    return c.f;
}
static __device__ __forceinline__ float bf_split(float f, unsigned short& h) {
    h = f2bf(f);
    return f - bf2f(h);
}
static __device__ __forceinline__ unsigned pack_rne(float a, float b) {
    return ((unsigned)f2bf(b) << 16) | f2bf(a);
}
// pack two Schraudolph bf16 bit-patterns (values positive, < 32768)
static __device__ __forceinline__ unsigned pack_bits(float a, float b) {
    return ((unsigned)(int)b << 16) | (unsigned)(int)a;
}

// ---------------------------------------------------------------------------
// Projections (proven, unchanged from R9).
//   Qpack[b][n][32] bf16 = [qh|ql|qh|0]  with q PRE-SCALED by QSCALE
//   Kpack[b][n][16] bf16 = [kh|kl]
//   vT[b][c][n] bf16 — V^T via MFMA (bf16 x staged once in LDS)
// grid: B*128 blocks (32-token tiles), 256 threads.
// ---------------------------------------------------------------------------
__global__ __launch_bounds__(256) void proj_kernel(
    const float* __restrict__ xg,
    const float* __restrict__ Wf, const float* __restrict__ bf_,
    const float* __restrict__ Wg, const float* __restrict__ bg,
    const float* __restrict__ Wh, const float* __restrict__ bh,
    unsigned short* __restrict__ Qp, unsigned short* __restrict__ Kp,
    unsigned short* __restrict__ vTg)
{
    __shared__ float xS[32 * 68];            // fp32 x tile (q/k path)
    __shared__ unsigned short xbS[32 * 72];  // bf16 x tile, 64 ch/row
    __shared__ float WfT[8 * 68];
    __shared__ float WgT[8 * 68];
    __shared__ unsigned short vtS[64 * 40];  // V^T tile [cout][32 tok + pad]

    const int t = threadIdx.x;
    const int b = blockIdx.x >> 7;
    const int n0 = (blockIdx.x & 127) * 32;

    const float* xrow = xg + ((size_t)b * NTOK + n0) * CCH;
    for (int f = t; f < 512; f += 256) {
        int r = f >> 4, c4 = (f & 15) * 4;
        float4 v = *(const float4*)(xrow + r * 64 + c4);
        *(float4*)(xS + r * 68 + c4) = v;
        uint2 pk = { pack_rne(v.x, v.y), pack_rne(v.z, v.w) };
        *(uint2*)(xbS + r * 72 + c4) = pk;
    }
    for (int e = t; e < 512; e += 256) {
        int ci = e >> 3, j = e & 7;
        WfT[j * 68 + ci] = Wf[e];
        WgT[j * 68 + ci] = Wg[e];
    }
    __syncthreads();

    const int w = t >> 6, lane = t & 63, ml = lane & 15, quad = lane >> 4;

    // ---- V^T via MFMA: wave w owns couts w*16..w*16+15
    {
        s16x8 a0, a1;   // A[m=cout][k=cin] = Wh[cin][cout]
        #pragma unroll
        for (int j = 0; j < 8; ++j) {
            a0[j] = (short)f2bf(Wh[(quad * 8 + j) * 64 + w * 16 + ml]);
            a1[j] = (short)f2bf(Wh[(32 + quad * 8 + j) * 64 + w * 16 + ml]);
        }
        #pragma unroll
        for (int nf = 0; nf < 2; ++nf) {
            int tok = nf * 16 + ml;
            s16x8 b0 = *(const s16x8*)(xbS + tok * 72 + quad * 8);
            s16x8 b1 = *(const s16x8*)(xbS + tok * 72 + 32 + quad * 8);
            f32x4 cc = __builtin_amdgcn_mfma_f32_16x16x32_bf16(a0, b0, (f32x4){0.f,0.f,0.f,0.f}, 0, 0, 0);
            cc = __builtin_amdgcn_mfma_f32_16x16x32_bf16(a1, b1, cc, 0, 0, 0);
            #pragma unroll
            for (int reg = 0; reg < 4; ++reg) {
                int cout = w * 16 + quad * 4 + reg;
                vtS[cout * 40 + nf * 16 + ml] = f2bf(cc[reg] + bh[cout]);
            }
        }
    }

    // ---- q/k: thread (r = t>>3, j = t&7): fp32 VALU + Dekker pack
    {
        int r = t >> 3, j = t & 7;
        float q = bf_[j], k = bg[j];
        for (int ci = 0; ci < 64; ci += 4) {
            float4 x4 = *(const float4*)(xS + r * 68 + ci);
            float4 wf4 = *(const float4*)(WfT + j * 68 + ci);
            float4 wg4 = *(const float4*)(WgT + j * 68 + ci);
            q += x4.x * wf4.x + x4.y * wf4.y + x4.z * wf4.z + x4.w * wf4.w;
            k += x4.x * wg4.x + x4.y * wg4.y + x4.z * wg4.z + x4.w * wg4.w;
        }
        q *= QSCALE;   // fold Schraudolph scale (128*log2e) into Q
        unsigned short qh, kh;
        float qres = bf_split(q, qh);
        float kres = bf_split(k, kh);
        unsigned short ql = f2bf(qres), kl = f2bf(kres);
        size_t qbase = ((size_t)b * NTOK + n0 + r) * 32;
        Qp[qbase + j]      = qh;
        Qp[qbase + 8 + j]  = ql;
        Qp[qbase + 16 + j] = qh;
        Qp[qbase + 24 + j] = 0;
        size_t kbase = ((size_t)b * NTOK + n0 + r) * 16;
        Kp[kbase + j]     = kh;
        Kp[kbase + 8 + j] = kl;
    }
    __syncthreads();

    // ---- coalesced vT store
    {
        int c_ = t >> 2, chunk = t & 3;
        uint4 v = *(const uint4*)(vtS + c_ * 40 + chunk * 8);
        *(uint4*)(vTg + ((size_t)b * CCH + c_) * NTOK + n0 + chunk * 8) = v;
    }
}

// ---------------------------------------------------------------------------
// Attention — R9 config (empirical optimum: KSPLIT=2, K in 64KB LDS,
// launch_bounds(256,2), 2 blocks/CU) + REGISTER-PIPELINED V: frags for tile
// i are loaded during iteration i-1 (vn->vc swap), so every V load has a
// full iteration of independent MFMA/pack work before use. No fences, no
// cross-block coherence (R13 showed __threadfence costs an L2 flush/block).
// grid = B*64*KSPLIT = 512 blocks, 256 thr.
// ---------------------------------------------------------------------------
__global__ __launch_bounds__(256, 2) void attn_kernel(
    const unsigned short* __restrict__ Qp,
    const unsigned short* __restrict__ Kp,
    const unsigned short* __restrict__ vTg,
    unsigned short* __restrict__ Opart,
    float* __restrict__ lpart)
{
    __shared__ unsigned short KC[KPB * 16];   // [key][kh8|kl8], 64 KB

    const int t = threadIdx.x;
    const int blk = blockIdx.x;
    const int b = blk >> 7;
    const int qt = (blk >> 1) & 63;
    const int ks = blk & 1;
    const int m0 = qt * 64;
    const int kb0 = ks * KPB;
    const int w = t >> 6, lane = t & 63;
    const int ml = lane & 15, quad = lane >> 4;

    const unsigned short* qpb = Qp + (size_t)b * NTOK * 32;
    const unsigned short* kpb = Kp + (size_t)b * NTOK * 16;
    const unsigned short* vtb = vTg + (size_t)b * CCH * NTOK;

    for (int kk = t; kk < KPB; kk += 256) {
        const unsigned short* src = kpb + (size_t)(kb0 + kk) * 16;
        *(uint4*)(&KC[kk * 16])     = *(const uint4*)(src);
        *(uint4*)(&KC[kk * 16 + 8]) = *(const uint4*)(src + 8);
    }

    s16x8 qf[4];
    #pragma unroll
    for (int qg = 0; qg < 4; ++qg)
        qf[qg] = *(const s16x8*)(qpb + (size_t)(m0 + qg * 16 + ml) * 32 + quad * 8);

    const int keyA = 8 * (ml >> 2) + (ml & 3);   // permuted key row
    const int khsel = (quad == 2) ? 8 : 0;       // quad0,1,3->kh  quad2->kl

    s16x8 ones;
    #pragma unroll
    for (int i = 0; i < 8; ++i) ones[i] = (short)0x3F80;

    f32x4 o[4][4];
    f32x4 lac[4];
    #pragma unroll
    for (int cg = 0; cg < 4; ++cg)
        #pragma unroll
        for (int qg = 0; qg < 4; ++qg) o[cg][qg] = (f32x4){0.f,0.f,0.f,0.f};
    #pragma unroll
    for (int qg = 0; qg < 4; ++qg) lac[qg] = (f32x4){0.f,0.f,0.f,0.f};
    const f32x4 sb = {SBIAS, SBIAS, SBIAS, SBIAS};   // Schraudolph bias seed

    const int tile0 = w * TPW;

    // V frags for tile0 (issued before the KC barrier -> deep in flight)
    s16x8 vc[4][2];
    #pragma unroll
    for (int cg = 0; cg < 4; ++cg) {
        const unsigned short* vr = vtb + (size_t)(cg * 16 + ml) * NTOK + (kb0 + tile0 * 64) + quad * 8;
        vc[cg][0] = *(const s16x8*)(vr);
        vc[cg][1] = *(const s16x8*)(vr + 32);
    }

    __syncthreads();   // KC visible; no more barriers until epilogue

    s16x8 kf0 = *(const s16x8*)(&KC[(tile0 * 64 + keyA) * 16 + khsel]);
    s16x8 kf1 = *(const s16x8*)(&KC[(tile0 * 64 + keyA + 4) * 16 + khsel]);
    s16x8 kf2 = *(const s16x8*)(&KC[(tile0 * 64 + 32 + keyA) * 16 + khsel]);
    s16x8 kf3 = *(const s16x8*)(&KC[(tile0 * 64 + 36 + keyA) * 16 + khsel]);

    for (int i = 0; i < TPW; ++i) {
        const int tile = tile0 + i;
        const int tn = (i + 1 < TPW) ? tile + 1 : tile0;

        // issue NEXT tile's V loads first (consumed next iteration)
        s16x8 vn[4][2];
        #pragma unroll
        for (int cg = 0; cg < 4; ++cg) {
            const unsigned short* vr = vtb + (size_t)(cg * 16 + ml) * NTOK + (kb0 + tn * 64) + quad * 8;
            vn[cg][0] = *(const s16x8*)(vr);
            vn[cg][1] = *(const s16x8*)(vr + 32);
        }
        // prefetch K frags for next tile (static LDS)
        s16x8 kn0 = *(const s16x8*)(&KC[(tn * 64 + keyA) * 16 + khsel]);
        s16x8 kn1 = *(const s16x8*)(&KC[(tn * 64 + keyA + 4) * 16 + khsel]);
        s16x8 kn2 = *(const s16x8*)(&KC[(tn * 64 + 32 + keyA) * 16 + khsel]);
        s16x8 kn3 = *(const s16x8*)(&KC[(tn * 64 + 36 + keyA) * 16 + khsel]);

        // S (bias-seeded) -> p bits via int cast; lands in PV B-layout
        union { unsigned u[4]; s16x8 h; } P0[4], P1[4];
        #pragma unroll
        for (int qg = 0; qg < 4; ++qg) {
            f32x4 sA0 = __builtin_amdgcn_mfma_f32_16x16x32_bf16(kf0, qf[qg], sb, 0, 0, 0);
            f32x4 sB0 = __builtin_amdgcn_mfma_f32_16x16x32_bf16(kf1, qf[qg], sb, 0, 0, 0);
            f32x4 sA1 = __builtin_amdgcn_mfma_f32_16x16x32_bf16(kf2, qf[qg], sb, 0, 0, 0);
            f32x4 sB1 = __builtin_amdgcn_mfma_f32_16x16x32_bf16(kf3, qf[qg], sb, 0, 0, 0);
            P0[qg].u[0] = pack_bits(sA0[0], sA0[1]);
            P0[qg].u[1] = pack_bits(sA0[2], sA0[3]);
            P0[qg].u[2] = pack_bits(sB0[0], sB0[1]);
            P0[qg].u[3] = pack_bits(sB0[2], sB0[3]);
            P1[qg].u[0] = pack_bits(sA1[0], sA1[1]);
            P1[qg].u[1] = pack_bits(sA1[2], sA1[3]);
            P1[qg].u[2] = pack_bits(sB1[0], sB1[1]);
            P1[qg].u[3] = pack_bits(sB1[2], sB1[3]);
        }
        kf0 = kn0; kf1 = kn1; kf2 = kn2; kf3 = kn3;

        // l += ones * P
        #pragma unroll
        for (int qg = 0; qg < 4; ++qg) {
            lac[qg] = __builtin_amdgcn_mfma_f32_16x16x32_bf16(ones, P0[qg].h, lac[qg], 0, 0, 0);
            lac[qg] = __builtin_amdgcn_mfma_f32_16x16x32_bf16(ones, P1[qg].h, lac[qg], 0, 0, 0);
        }
        // O^T += V^T * P   (V frags loaded LAST iteration -> latency hidden)
        #pragma unroll
        for (int cg = 0; cg < 4; ++cg)
            #pragma unroll
            for (int qg = 0; qg < 4; ++qg) {
                o[cg][qg] = __builtin_amdgcn_mfma_f32_16x16x32_bf16(vc[cg][0], P0[qg].h, o[cg][qg], 0, 0, 0);
                o[cg][qg] = __builtin_amdgcn_mfma_f32_16x16x32_bf16(vc[cg][1], P1[qg].h, o[cg][qg], 0, 0, 0);
            }
        // rotate pipeline
        #pragma unroll
        for (int cg = 0; cg < 4; ++cg) {
            vc[cg][0] = vn[cg][0];
            vc[cg][1] = vn[cg][1];
        }
    }

    // ---- epilogue: fp32 reduction across 4 waves via LDS (reuse KC)
    float* OL = (float*)KC;          // [64 query][68], 17.4 KB
    float* lL = OL + 64 * 68;        // [64]
    #pragma unroll
    for (int r = 0; r < 4; ++r) {
        __syncthreads();
        if (w == r) {
            #pragma unroll
            for (int cg = 0; cg < 4; ++cg)
                #pragma unroll
                for (int qg = 0; qg < 4; ++qg) {
                    f32x4* p = (f32x4*)(&OL[(qg * 16 + ml) * 68 + cg * 16 + quad * 4]);
                    if (r == 0) *p = o[cg][qg];
                    else {
                        f32x4 v = *p;
                        v[0] += o[cg][qg][0]; v[1] += o[cg][qg][1];
                        v[2] += o[cg][qg][2]; v[3] += o[cg][qg][3];
                        *p = v;
                    }
                }
            if (quad == 0) {
                #pragma unroll
                for (int qg = 0; qg < 4; ++qg) {
                    if (r == 0) lL[qg * 16 + ml] = lac[qg][0];
                    else        lL[qg * 16 + ml] += lac[qg][0];
                }
            }
        }
    }
    __syncthreads();

    {
        int q = t >> 2, c0 = (t & 3) * 16;
        alignas(16) unsigned short us[16];
        #pragma unroll
        for (int k = 0; k < 16; ++k) us[k] = f2bf(OL[q * 68 + c0 + k]);
        size_t obase = ((size_t)ks * (BATCH * NTOK) + (size_t)b * NTOK + m0 + q) * 64 + c0;
        *(uint4*)(Opart + obase)     = *(uint4*)(us);
        *(uint4*)(Opart + obase + 8) = *(uint4*)(us + 8);
    }
    if (t < 64)
        lpart[ks * (BATCH * NTOK) + b * NTOK + m0 + t] = lL[t];
}

// ---------------------------------------------------------------------------
// Combine: out = gamma * (sum_s O_s) / (sum_s l_s) + x.  1024 blocks x 256.
// ---------------------------------------------------------------------------
__global__ __launch_bounds__(256) void combine_kernel(
    const float* __restrict__ xg,
    const unsigned short* __restrict__ Opart,
    const float* __restrict__ lpart,
    const float* __restrict__ gammaPtr,
    float* __restrict__ out)
{
    const int i4 = blockIdx.x * 256 + threadIdx.x;
    const int base = i4 * 4;
    const int tok = base >> 6;

    float lsum = 0.f;
    #pragma unroll
    for (int s = 0; s < KSPLIT; ++s)
        lsum += lpart[s * (BATCH * NTOK) + tok];

    float o0 = 0.f, o1 = 0.f, o2 = 0.f, o3 = 0.f;
    #pragma unroll
    for (int s = 0; s < KSPLIT; ++s) {
        uint2 u = *(const uint2*)(Opart + (size_t)s * (BATCH * NTOK * 64) + base);
        o0 += bf2f((unsigned short)(u.x & 0xFFFF));
        o1 += bf2f((unsigned short)(u.x >> 16));
        o2 += bf2f((unsigned short)(u.y & 0xFFFF));
        o3 += bf2f((unsigned short)(u.y >> 16));
    }
    const float4 x4 = *(const float4*)(xg + base);
    const float gi = gammaPtr[0] / lsum;
    float4 r;
    r.x = gi * o0 + x4.x;
    r.y = gi * o1 + x4.y;
    r.z = gi * o2 + x4.z;
    r.w = gi * o3 + x4.w;
    *(float4*)(out + base) = r;
}

extern "C" void kernel_launch(void* const* d_in, const int* in_sizes, int n_in,
                              void* d_out, int out_size, void* d_ws, size_t ws_size,
                              hipStream_t stream) {
    const float* x  = (const float*)d_in[0];
    const float* Wf = (const float*)d_in[1];
    const float* bf = (const float*)d_in[2];
    const float* Wg = (const float*)d_in[3];
    const float* bg = (const float*)d_in[4];
    const float* Wh = (const float*)d_in[5];
    const float* bh = (const float*)d_in[6];
    const float* gamma = (const float*)d_in[7];
    float* out = (float*)d_out;

    // ws: Qp 1MB @0 | Kp 512KB @1MB | vT 2MB @2MB | Opart 4MB @4MB | lpart @8MB
    char* ws = (char*)d_ws;
    unsigned short* Qp    = (unsigned short*)ws;
    unsigned short* Kp    = (unsigned short*)(ws + (1u << 20));
    unsigned short* vTg   = (unsigned short*)(ws + (2u << 20));
    unsigned short* Opart = (unsigned short*)(ws + (4u << 20));
    float*          lpart = (float*)(ws + (8u << 20));

    proj_kernel<<<BATCH * 128, 256, 0, stream>>>(x, Wf, bf, Wg, bg, Wh, bh,
                                                 Qp, Kp, vTg);
    attn_kernel<<<BATCH * 64 * KSPLIT, 256, 0, stream>>>(Qp, Kp, vTg, Opart, lpart);
    combine_kernel<<<(BATCH * NTOK * CCH) / 1024, 256, 0, stream>>>(x, Opart, lpart, gamma, out);
}